// Round 12
// baseline (296.507 us; speedup 1.0000x reference)
//
#include <hip/hip_runtime.h>
#include <hip/hip_cooperative_groups.h>
#include <math.h>

namespace cg = cooperative_groups;

#define HB 64      // batch
#define HD 1024    // hidden / input dim
#define KSF 256    // K-slice per split-K block (front chain)
#define KSB 128    // K-slice (back chain)
#define XS 68      // padded LDS row stride (floats)

typedef float f32x4 __attribute__((ext_vector_type(4)));

// ---------------------------------------------------------------------------
// Split-K register-tiled GEMM slice with register prefetch (R10-exact):
//   P[b][m0+mj] = sum_{n=k0..k0+KS-1} X[b][n] * W[m][n]
// Block 256 thr, tile 64b x 64m, thread (bx=t&15, my=t>>4) owns 4b x 4m.
// ---------------------------------------------------------------------------
template<int KS>
__device__ __forceinline__ void splitk_tile(
    const float* __restrict__ X0, int noff,
    const float* __restrict__ W, int K,
    int m0, int k0,
    float* __restrict__ P)
{
    __shared__ __align__(16) float Xs[32][XS];
    __shared__ __align__(16) float Ws[32][XS];
    const int t  = threadIdx.x;
    const int bx = t & 15;
    const int my = t >> 4;
    float acc[4][4] = {};

    float4 xp[2], wp[2];
    #pragma unroll
    for (int i = 0; i < 2; ++i) {
        int u = t + 256 * i;
        int r = u >> 3, nq = u & 7;
        xp[i] = *(const float4*)&X0[r * HD + (k0 - noff) + nq * 4];
        wp[i] = *(const float4*)&W[(long long)(m0 + r) * K + k0 + nq * 4];
    }

    for (int kc = 0; kc < KS; kc += 32) {
        #pragma unroll
        for (int i = 0; i < 2; ++i) {
            int u = t + 256 * i;
            int r = u >> 3, nq = u & 7;
            Xs[nq * 4 + 0][r] = xp[i].x; Xs[nq * 4 + 1][r] = xp[i].y;
            Xs[nq * 4 + 2][r] = xp[i].z; Xs[nq * 4 + 3][r] = xp[i].w;
            Ws[nq * 4 + 0][r] = wp[i].x; Ws[nq * 4 + 1][r] = wp[i].y;
            Ws[nq * 4 + 2][r] = wp[i].z; Ws[nq * 4 + 3][r] = wp[i].w;
        }
        __syncthreads();
        if (kc + 32 < KS) {
            const int n0 = k0 + kc + 32;
            #pragma unroll
            for (int i = 0; i < 2; ++i) {
                int u = t + 256 * i;
                int r = u >> 3, nq = u & 7;
                xp[i] = *(const float4*)&X0[r * HD + (n0 - noff) + nq * 4];
                wp[i] = *(const float4*)&W[(long long)(m0 + r) * K + n0 + nq * 4];
            }
        }
        #pragma unroll
        for (int n = 0; n < 32; ++n) {
            float4 xv = *(const float4*)&Xs[n][bx * 4];
            float4 wv = *(const float4*)&Ws[n][my * 4];
            float xe[4] = {xv.x, xv.y, xv.z, xv.w};
            float we[4] = {wv.x, wv.y, wv.z, wv.w};
            #pragma unroll
            for (int i = 0; i < 4; ++i)
                #pragma unroll
                for (int j = 0; j < 4; ++j)
                    acc[i][j] = fmaf(xe[i], we[j], acc[i][j]);
        }
        __syncthreads();
    }
    #pragma unroll
    for (int i = 0; i < 4; ++i) {
        float4 o4 = make_float4(acc[i][0], acc[i][1], acc[i][2], acc[i][3]);
        *(float4*)&P[(bx * 4 + i) * HD + m0 + my * 4] = o4;
    }
}

// ---------------------------------------------------------------------------
// Fused front chain (cooperative): GEMM phase (448 blocks = 16 m-tiles x 28
// (gemm,split) units) -> grid.sync -> float4 reduce+bias+sigmoid phase.
// Bodies byte-identical to R10's qkvfi_splitk / reduce_qkvfi.
// ---------------------------------------------------------------------------
struct FrontArgs {
    const float *x, *h, *Wq, *Wk, *Wv, *Wf, *Wi;
    const float *bq, *bk, *bv, *bf, *bi;
    float *P, *q, *k, *v, *fg, *ig;
};

__global__ __launch_bounds__(256) void front_fused(FrontArgs a)
{
    const int bid = blockIdx.x;          // 0..447
    const int gy  = bid >> 4;            // 0..27
    const int mt  = bid & 15;
    {
        const float* W; int K, split;
        if (gy < 12) {
            int g = gy >> 2; split = gy & 3; K = HD;
            W = (g == 0) ? a.Wq : (g == 1) ? a.Wk : a.Wv;
        } else {
            int tt = gy - 12; int g = tt >> 3; split = tt & 7; K = 2 * HD;
            W = g ? a.Wi : a.Wf;
        }
        const int k0 = split * KSF;
        const float* X0; int noff;
        if (k0 < HD) { X0 = a.x; noff = 0; } else { X0 = a.h; noff = HD; }
        splitk_tile<KSF>(X0, noff, W, K, mt * 64, k0,
                         a.P + (size_t)gy * (HB * HD));
    }
    __threadfence();
    cg::this_grid().sync();

    // reduce phase: 448*256 = 114688 threads cover 81920 float4 units
    const int o4 = bid * 256 + threadIdx.x;
    if (o4 < 81920) {
        const int g  = o4 >> 14;
        const int r4 = o4 & 16383;
        const int m4 = r4 & 255;
        int base, ns, act; const float* bias; float* out;
        switch (g) {
            case 0:  base = 0;  ns = 4; bias = a.bq; out = a.q;  act = 0; break;
            case 1:  base = 4;  ns = 4; bias = a.bk; out = a.k;  act = 0; break;
            case 2:  base = 8;  ns = 4; bias = a.bv; out = a.v;  act = 0; break;
            case 3:  base = 12; ns = 8; bias = a.bf; out = a.fg; act = 1; break;
            default: base = 20; ns = 8; bias = a.bi; out = a.ig; act = 1; break;
        }
        float4 s = ((const float4*)bias)[m4];
        const float4* P4 = (const float4*)a.P;
        for (int i = 0; i < ns; ++i) {
            float4 p = P4[(size_t)(base + i) * 16384 + r4];
            s.x += p.x; s.y += p.y; s.z += p.z; s.w += p.w;
        }
        if (act) {
            s.x = 1.0f / (1.0f + expf(-s.x)); s.y = 1.0f / (1.0f + expf(-s.y));
            s.z = 1.0f / (1.0f + expf(-s.z)); s.w = 1.0f / (1.0f + expf(-s.w));
        }
        ((float4*)out)[r4] = s;
    }
}

// ---------------------------------------------------------------------------
// Fused back chain (cooperative): out GEMM (128 blocks) -> grid.sync ->
// float4 reduce+bias. Bodies byte-identical to R10's out_splitk / reduce_out.
// ---------------------------------------------------------------------------
struct BackArgs {
    const float *tr, *Wo, *bo;
    float *P2, *hnew;
};

__global__ __launch_bounds__(256) void back_fused(BackArgs a)
{
    const int bid   = blockIdx.x;        // 0..127
    const int split = bid >> 4;          // 0..7
    const int mt    = bid & 15;
    splitk_tile<KSB>(a.tr, 0, a.Wo, HD, mt * 64, split * KSB,
                     a.P2 + (size_t)split * (HB * HD));
    __threadfence();
    cg::this_grid().sync();

    const int o4 = bid * 256 + threadIdx.x;   // 32768 threads cover 16384 units
    if (o4 < 16384) {
        const int m4 = o4 & 255;
        float4 s = ((const float4*)a.bo)[m4];
        const float4* P4 = (const float4*)a.P2;
        #pragma unroll
        for (int i = 0; i < 8; ++i) {
            float4 p = P4[(size_t)i * 16384 + o4];
            s.x += p.x; s.y += p.y; s.z += p.z; s.w += p.w;
        }
        ((float4*)a.hnew)[o4] = s;
    }
}

// ---------------------------------------------------------------------------
// Fused C update + readout (R11-exact — best measured, NT-load/plain-store):
//   Cn[b,m,n] = f[b,m]*C[b,m,n] + (i[b,m]*k[b,m])*v[b,n]
//   tr[b,m]   = tanh( sum_n Cn[b,m,n] * q[b,n] )
// ---------------------------------------------------------------------------
__global__ __launch_bounds__(256) void update_kernel(
    const float* __restrict__ C,
    const float* __restrict__ q, const float* __restrict__ k,
    const float* __restrict__ v, const float* __restrict__ fg,
    const float* __restrict__ ig,
    float* __restrict__ Cn, float* __restrict__ tr)
{
    __shared__ __align__(16) float qs[HD];
    __shared__ __align__(16) float vs[HD];
    const int t    = threadIdx.x;
    const int wid  = t >> 6;
    const int lane = t & 63;
    const int row  = blockIdx.x * 4 + wid;      // 0 .. B*HD-1
    const int b    = row >> 10;                 // same for all 4 rows (4|1024)
    const int m    = row & (HD - 1);

    ((float4*)qs)[t] = ((const float4*)q)[b * 256 + t];
    ((float4*)vs)[t] = ((const float4*)v)[b * 256 + t];

    const float fm  = fg[b * HD + m];
    const float ikm = ig[b * HD + m] * k[b * HD + m];
    __syncthreads();

    const f32x4* C4 = (const f32x4*)C;
    const f32x4* V4 = (const f32x4*)vs;
    const f32x4* Q4 = (const f32x4*)qs;
    f32x4*       N4 = (f32x4*)Cn;

    const int base = row * (HD / 4);

    float racc = 0.f;
    #pragma unroll
    for (int j = 0; j < 4; ++j) {
        int o = lane + 64 * j;
        f32x4 c4 = __builtin_nontemporal_load(&C4[base + o]);
        f32x4 v4 = V4[o];
        f32x4 q4 = Q4[o];
        f32x4 cn;
        cn.x = fmaf(fm, c4.x, ikm * v4.x);
        cn.y = fmaf(fm, c4.y, ikm * v4.y);
        cn.z = fmaf(fm, c4.z, ikm * v4.z);
        cn.w = fmaf(fm, c4.w, ikm * v4.w);
        N4[base + o] = cn;                      // plain cached store
        racc += cn.x * q4.x + cn.y * q4.y + cn.z * q4.z + cn.w * q4.w;
    }
    #pragma unroll
    for (int off = 32; off; off >>= 1) racc += __shfl_xor(racc, off);
    if (lane == 0) tr[row] = tanhf(racc);
}

extern "C" void kernel_launch(void* const* d_in, const int* in_sizes, int n_in,
                              void* d_out, int out_size, void* d_ws, size_t ws_size,
                              hipStream_t stream) {
    const float* x  = (const float*)d_in[0];
    const float* h  = (const float*)d_in[1];
    const float* C  = (const float*)d_in[2];
    const float* Wq = (const float*)d_in[3];
    const float* bq = (const float*)d_in[4];
    const float* Wk = (const float*)d_in[5];
    const float* bk = (const float*)d_in[6];
    const float* Wv = (const float*)d_in[7];
    const float* bv = (const float*)d_in[8];
    const float* Wf = (const float*)d_in[9];
    const float* bf = (const float*)d_in[10];
    const float* Wi = (const float*)d_in[11];
    const float* bi = (const float*)d_in[12];
    const float* Wo = (const float*)d_in[13];
    const float* bo = (const float*)d_in[14];

    float* outp = (float*)d_out;
    float* hnew = outp;                    // [B,HD]
    float* Cn   = outp + HB * HD;          // [B,HD,HD]

    const size_t SL = (size_t)HB * HD;     // 65536
    float* ws = (float*)d_ws;
    float* q  = ws + 0 * SL;
    float* k  = ws + 1 * SL;
    float* v  = ws + 2 * SL;
    float* fg = ws + 3 * SL;
    float* ig = ws + 4 * SL;
    float* tr = ws + 5 * SL;
    float* P  = ws + 6 * SL;               // 28 slabs (KS=256)
    float* P2 = ws + 34 * SL;              // 8 slabs  (KS=128)

    FrontArgs fa = { x, h, Wq, Wk, Wv, Wf, Wi,
                     bq, bk, bv, bf, bi,
                     P, q, k, v, fg, ig };
    void* fparams[] = { &fa };
    hipLaunchCooperativeKernel((const void*)front_fused,
                               dim3(448), dim3(256), fparams, 0, stream);

    update_kernel<<<dim3((HB * HD) / 4), 256, 0, stream>>>(
        C, q, k, v, fg, ig, Cn, tr);

    BackArgs ba = { tr, Wo, bo, P2, hnew };
    void* bparams[] = { &ba };
    hipLaunchCooperativeKernel((const void*)back_fused,
                               dim3(128), dim3(256), bparams, 0, stream);
}

// Round 13
// 127.036 us; speedup vs baseline: 2.3340x; 2.3340x over previous
//
#include <hip/hip_runtime.h>
#include <math.h>

#define HB 64      // batch
#define HD 1024    // hidden / input dim
#define KSF 256    // K-slice per split-K block (front chain)
#define KSB 128    // K-slice (back chain)
#define XS 68      // padded LDS row stride (floats)

typedef float f32x4 __attribute__((ext_vector_type(4)));

// ---------------------------------------------------------------------------
// Split-K register-tiled GEMM slice with register prefetch (R10-exact):
//   P[b][m0+mj] = sum_{n=k0..k0+KS-1} X[b][n] * W[m][n]
// ---------------------------------------------------------------------------
template<int KS>
__device__ __forceinline__ void splitk_tile(
    const float* __restrict__ X0, int noff,
    const float* __restrict__ W, int K,
    int m0, int k0,
    float* __restrict__ P)
{
    __shared__ __align__(16) float Xs[32][XS];
    __shared__ __align__(16) float Ws[32][XS];
    const int t  = threadIdx.x;
    const int bx = t & 15;
    const int my = t >> 4;
    float acc[4][4] = {};

    float4 xp[2], wp[2];
    #pragma unroll
    for (int i = 0; i < 2; ++i) {
        int u = t + 256 * i;
        int r = u >> 3, nq = u & 7;
        xp[i] = *(const float4*)&X0[r * HD + (k0 - noff) + nq * 4];
        wp[i] = *(const float4*)&W[(long long)(m0 + r) * K + k0 + nq * 4];
    }

    for (int kc = 0; kc < KS; kc += 32) {
        #pragma unroll
        for (int i = 0; i < 2; ++i) {
            int u = t + 256 * i;
            int r = u >> 3, nq = u & 7;
            Xs[nq * 4 + 0][r] = xp[i].x; Xs[nq * 4 + 1][r] = xp[i].y;
            Xs[nq * 4 + 2][r] = xp[i].z; Xs[nq * 4 + 3][r] = xp[i].w;
            Ws[nq * 4 + 0][r] = wp[i].x; Ws[nq * 4 + 1][r] = wp[i].y;
            Ws[nq * 4 + 2][r] = wp[i].z; Ws[nq * 4 + 3][r] = wp[i].w;
        }
        __syncthreads();
        if (kc + 32 < KS) {
            const int n0 = k0 + kc + 32;
            #pragma unroll
            for (int i = 0; i < 2; ++i) {
                int u = t + 256 * i;
                int r = u >> 3, nq = u & 7;
                xp[i] = *(const float4*)&X0[r * HD + (n0 - noff) + nq * 4];
                wp[i] = *(const float4*)&W[(long long)(m0 + r) * K + n0 + nq * 4];
            }
        }
        #pragma unroll
        for (int n = 0; n < 32; ++n) {
            float4 xv = *(const float4*)&Xs[n][bx * 4];
            float4 wv = *(const float4*)&Ws[n][my * 4];
            float xe[4] = {xv.x, xv.y, xv.z, xv.w};
            float we[4] = {wv.x, wv.y, wv.z, wv.w};
            #pragma unroll
            for (int i = 0; i < 4; ++i)
                #pragma unroll
                for (int j = 0; j < 4; ++j)
                    acc[i][j] = fmaf(xe[i], we[j], acc[i][j]);
        }
        __syncthreads();
    }
    #pragma unroll
    for (int i = 0; i < 4; ++i) {
        float4 o4 = make_float4(acc[i][0], acc[i][1], acc[i][2], acc[i][3]);
        *(float4*)&P[(bx * 4 + i) * HD + m0 + my * 4] = o4;
    }
}

// grid.x = 16 m-tiles; grid.y = 28 (gemm,split) units, KS=256:
//   gy 0..11 : q/k/v (4 splits each); gy 12..27 : f/i (8 splits each)
// Slab bases: q=0, k=4, v=8, f=12, i=20.
__global__ __launch_bounds__(256) void qkvfi_splitk(
    const float* __restrict__ x, const float* __restrict__ h,
    const float* __restrict__ Wq, const float* __restrict__ Wk,
    const float* __restrict__ Wv, const float* __restrict__ Wf,
    const float* __restrict__ Wi, float* __restrict__ P)
{
    const int gy = blockIdx.y;
    const float* W; int K, split;
    if (gy < 12) {
        int g = gy >> 2; split = gy & 3; K = HD;
        W = (g == 0) ? Wq : (g == 1) ? Wk : Wv;
    } else {
        int tt = gy - 12; int g = tt >> 3; split = tt & 7; K = 2 * HD;
        W = g ? Wi : Wf;
    }
    const int k0 = split * KSF;
    const float* X0; int noff;
    if (k0 < HD) { X0 = x; noff = 0; } else { X0 = h; noff = HD; }
    splitk_tile<KSF>(X0, noff, W, K, blockIdx.x * 64, k0,
                     P + (size_t)gy * (HB * HD));
}

__global__ __launch_bounds__(256) void out_splitk(
    const float* __restrict__ tr, const float* __restrict__ Wo,
    float* __restrict__ P2)
{
    const int split = blockIdx.y;   // 0..7
    splitk_tile<KSB>(tr, 0, Wo, HD, blockIdx.x * 64, split * KSB,
                     P2 + (size_t)split * (HB * HD));
}

__global__ __launch_bounds__(256) void reduce_out(
    const float* __restrict__ P2, const float* __restrict__ bo,
    float* __restrict__ hnew)
{
    const int o4 = blockIdx.x * 256 + threadIdx.x;   // 0..16383
    const int m4 = o4 & 255;
    float4 s = ((const float4*)bo)[m4];
    const float4* P4 = (const float4*)P2;
    #pragma unroll
    for (int i = 0; i < 8; ++i) {
        float4 p = P4[(size_t)i * 16384 + o4];
        s.x += p.x; s.y += p.y; s.z += p.z; s.w += p.w;
    }
    ((float4*)hnew)[o4] = s;
}

// ---------------------------------------------------------------------------
// Fused reduce + C update + readout. Replaces reduce_qkvfi + update_kernel:
// each block reduces its own q[b,:], v[b,:] (4 slabs + bias, L2-resident,
// same summation order as the old reduce kernel) into LDS, threads 0..3
// reduce per-row f/i/k scalars + sigmoid, then the R11-exact main loop
// (NT C-load, plain Cn store, LDS q/v, shuffle-reduced tanh readout).
//   Cn[b,m,n] = f[b,m]*C[b,m,n] + (i[b,m]*k[b,m])*v[b,n]
//   tr[b,m]   = tanh( sum_n Cn[b,m,n] * q[b,n] )
// ---------------------------------------------------------------------------
__global__ __launch_bounds__(256) void update_fused(
    const float* __restrict__ C, const float* __restrict__ P,
    const float* __restrict__ bq, const float* __restrict__ bk,
    const float* __restrict__ bv, const float* __restrict__ bf,
    const float* __restrict__ bi,
    float* __restrict__ Cn, float* __restrict__ tr)
{
    __shared__ __align__(16) float qs[HD];
    __shared__ __align__(16) float vs[HD];
    __shared__ float fs[4], iks[4];
    const int t    = threadIdx.x;
    const int wid  = t >> 6;
    const int lane = t & 63;
    const int row  = blockIdx.x * 4 + wid;      // 0 .. B*HD-1
    const int b    = row >> 10;                 // same for all 4 rows
    const int rb   = b * 256;                   // float4 base of row b

    // q[b,:], v[b,:]: bias + 4 slabs each (float4 unit t = 0..255)
    const float4* P4 = (const float4*)P;
    {
        float4 sq = ((const float4*)bq)[t];
        float4 sv = ((const float4*)bv)[t];
        #pragma unroll
        for (int i = 0; i < 4; ++i) {
            float4 p = P4[(size_t)(0 + i) * 16384 + rb + t];
            sq.x += p.x; sq.y += p.y; sq.z += p.z; sq.w += p.w;
            float4 r = P4[(size_t)(8 + i) * 16384 + rb + t];
            sv.x += r.x; sv.y += r.y; sv.z += r.z; sv.w += r.w;
        }
        ((float4*)qs)[t] = sq;
        ((float4*)vs)[t] = sv;
    }
    // per-row f, i*k (threads 0..3, one row each)
    if (t < 4) {
        const int rr = blockIdx.x * 4 + t;
        const int mm = rr & (HD - 1);
        const int e  = b * HD + mm;
        float fv = bf[mm], iv = bi[mm], kv = bk[mm];
        #pragma unroll
        for (int i = 0; i < 8; ++i) {
            fv += P[(size_t)(12 + i) * 65536 + e];
            iv += P[(size_t)(20 + i) * 65536 + e];
        }
        #pragma unroll
        for (int i = 0; i < 4; ++i)
            kv += P[(size_t)(4 + i) * 65536 + e];
        fv = 1.0f / (1.0f + expf(-fv));
        iv = 1.0f / (1.0f + expf(-iv));
        fs[t]  = fv;
        iks[t] = iv * kv;
    }
    __syncthreads();

    const float fm  = fs[wid];
    const float ikm = iks[wid];

    const f32x4* C4 = (const f32x4*)C;
    const f32x4* V4 = (const f32x4*)vs;
    const f32x4* Q4 = (const f32x4*)qs;
    f32x4*       N4 = (f32x4*)Cn;

    const int base = row * (HD / 4);

    float racc = 0.f;
    #pragma unroll
    for (int j = 0; j < 4; ++j) {
        int o = lane + 64 * j;
        f32x4 c4 = __builtin_nontemporal_load(&C4[base + o]);
        f32x4 v4 = V4[o];
        f32x4 q4 = Q4[o];
        f32x4 cn;
        cn.x = fmaf(fm, c4.x, ikm * v4.x);
        cn.y = fmaf(fm, c4.y, ikm * v4.y);
        cn.z = fmaf(fm, c4.z, ikm * v4.z);
        cn.w = fmaf(fm, c4.w, ikm * v4.w);
        N4[base + o] = cn;                      // plain cached store
        racc += cn.x * q4.x + cn.y * q4.y + cn.z * q4.z + cn.w * q4.w;
    }
    #pragma unroll
    for (int off = 32; off; off >>= 1) racc += __shfl_xor(racc, off);
    if (lane == 0) tr[row] = tanhf(racc);
}

extern "C" void kernel_launch(void* const* d_in, const int* in_sizes, int n_in,
                              void* d_out, int out_size, void* d_ws, size_t ws_size,
                              hipStream_t stream) {
    const float* x  = (const float*)d_in[0];
    const float* h  = (const float*)d_in[1];
    const float* C  = (const float*)d_in[2];
    const float* Wq = (const float*)d_in[3];
    const float* bq = (const float*)d_in[4];
    const float* Wk = (const float*)d_in[5];
    const float* bk = (const float*)d_in[6];
    const float* Wv = (const float*)d_in[7];
    const float* bv = (const float*)d_in[8];
    const float* Wf = (const float*)d_in[9];
    const float* bf = (const float*)d_in[10];
    const float* Wi = (const float*)d_in[11];
    const float* bi = (const float*)d_in[12];
    const float* Wo = (const float*)d_in[13];
    const float* bo = (const float*)d_in[14];

    float* outp = (float*)d_out;
    float* hnew = outp;                    // [B,HD]
    float* Cn   = outp + HB * HD;          // [B,HD,HD]

    const size_t SL = (size_t)HB * HD;     // 65536
    float* ws = (float*)d_ws;
    float* tr = ws + 0 * SL;
    float* P  = ws + 1 * SL;               // 28 slabs (KS=256)
    float* P2 = ws + 29 * SL;              // 8 slabs  (KS=128)

    qkvfi_splitk<<<dim3(16, 28), 256, 0, stream>>>(x, h, Wq, Wk, Wv, Wf, Wi, P);
    update_fused<<<dim3((HB * HD) / 4), 256, 0, stream>>>(
        C, P, bq, bk, bv, bf, bi, Cn, tr);
    out_splitk<<<dim3(16, 8), 256, 0, stream>>>(tr, Wo, P2);
    reduce_out<<<dim3(64), 256, 0, stream>>>(P2, bo, hnew);
}